// Round 5
// baseline (33237.158 us; speedup 1.0000x reference)
//
#include <hip/hip_runtime.h>

namespace {

constexpr int kT = 256;

typedef float f4 __attribute__((ext_vector_type(4)));

__device__ __forceinline__ float fast_tanh(float x) {
    float e = __expf(2.0f * x);
    return 1.0f - 2.0f * __builtin_amdgcn_rcpf(e + 1.0f);
}

__device__ __forceinline__ float dpp_xor1(float x) {
    return __builtin_bit_cast(float, __builtin_amdgcn_update_dpp(
        0, __builtin_bit_cast(int, x), 0xB1, 0xF, 0xF, true)); // quad [1,0,3,2]
}
__device__ __forceinline__ float dpp_xor2(float x) {
    return __builtin_bit_cast(float, __builtin_amdgcn_update_dpp(
        0, __builtin_bit_cast(int, x), 0x4E, 0xF, 0xF, true)); // quad [2,3,0,1]
}
__device__ __forceinline__ float dpp_ror8(float x) {           // lane ^ 8 within row16
    return __builtin_bit_cast(float, __builtin_amdgcn_update_dpp(
        0, __builtin_bit_cast(int, x), 0x128, 0xF, 0xF, true)); // row_ror:8
}
template <int PAT>
__device__ __forceinline__ float swz(float x) {
    return __builtin_bit_cast(float,
        __builtin_amdgcn_ds_swizzle(__builtin_bit_cast(int, x), PAT));
}
__device__ __forceinline__ float read_lane(float x, int lane) {
    return __builtin_bit_cast(float,
        __builtin_amdgcn_readlane(__builtin_bit_cast(int, x), lane));
}

// h storage is r-major: element (j, r) at float offset 4*j + 4*(j>>3) + r.
// One ds_read_b128 at k yields h[k][r=0..3] (no k-parity horizontal add);
// pad 4*(j>>3) keeps GEMM traffic <=2-way.
__device__ __forceinline__ int haddr(int j, int r) {
    return 4 * j + 4 * (j >> 3) + r;
}

// NOTE on VGPR budget: __launch_bounds__ MUST be (512, 1). The min-waves=2
// variant caps the allocator at 128 VGPRs; this core (f4 accumulators + 24
// quad-aligned f4 weight tuples) needs slightly more, and under the cap the
// allocator spills the whole weight array to scratch (measured r1/r2:
// 59 GB FETCH/dispatch, 20x slowdown). Grid is 1 block/CU (8 waves), so
// up to 256 VGPR still sustains the 2 waves/SIMD we actually run.
__global__ __launch_bounds__(512, 1) void hybrid_ode_kernel(
    const float* __restrict__ y0,
    const float* __restrict__ t_span,
    const float* __restrict__ meal,
    const float* __restrict__ tvns,
    const float* __restrict__ W_in, const float* __restrict__ b_in,
    const float* __restrict__ W_h,  const float* __restrict__ b_h,
    const float* __restrict__ W_out,const float* __restrict__ b_out,
    float* __restrict__ out)
{
    const int tid = threadIdx.x;
    const int w   = tid >> 6;          // wave 0..7
    const int l   = tid & 63;
    const int jgl = l >> 4;            // 0..3 j-group within wave
    const int kc  = l & 15;            // k-chunk (8 k's)
    const int kch = kc >> 2;           // high 2 bits of kc (j-XOR key)
    const int jg  = w * 4 + jgl;       // 0..31
    const int jb  = jg * 4;            // thread's 4 j's: jb..jb+3 (XOR-permuted)
    const int rw  = w & 3;             // RK row this wave carries
    const int row = blockIdx.x * 4 + rw;

    // produced output slot after reduce-scatter: out index == kc
    const int r_p = kc & 3;
    const int j_p = jb + kch;
    const int waddr = haddr(j_p, r_p);
    const bool pb0 = (kc & 1) != 0;
    const bool pb1 = (kc & 2) != 0;

    __shared__ __align__(16) float hp0[576];
    __shared__ __align__(16) float hp1[576];
    __shared__ __align__(16) float xbuf[4 * 16];

    // ---- one-time weight staging into registers.
    // wgt[ll][kk][pj] = W_h[ll][8*kc+kk][jb + (pj ^ kch)] : the j-XOR makes the
    // two j-stages of the butterfly uniform (no keep/give selects).
    f4 wgt[3][8];
    #pragma unroll
    for (int ll = 0; ll < 3; ++ll)
        #pragma unroll
        for (int kk = 0; kk < 8; ++kk) {
            const float* p = W_h + (size_t)(ll * 128 + 8 * kc + kk) * 128 + jb;
            f4 v;
            v.x = p[0 ^ kch];
            v.y = p[1 ^ kch];
            v.z = p[2 ^ kch];
            v.w = p[3 ^ kch];
            wgt[ll][kk] = v;
        }

    float win[9];
    #pragma unroll
    for (int k = 0; k < 9; ++k) win[k] = W_in[k * 128 + j_p];
    const float bin = b_in[j_p];
    float bh[3];
    #pragma unroll
    for (int ll = 0; ll < 3; ++ll) bh[ll] = b_h[ll * 128 + j_p];

    // output layer: XOR-permuted weights for a 3-bit reduce-scatter (s lands at l&7)
    const int s8 = l & 7;
    float wo0p[8], wo1p[8];
    #pragma unroll
    for (int p = 0; p < 8; ++p) {
        const int q = p ^ s8;
        wo0p[p] = (q < 6) ? W_out[l * 6 + q] : 0.0f;
        wo1p[p] = (q < 6) ? W_out[(l + 64) * 6 + q] : 0.0f;
    }
    float bo[6];
    #pragma unroll
    for (int s = 0; s < 6; ++s) bo[s] = b_out[s];
    const int oaddrA = haddr(l, 0);        // + rw at use
    const int oaddrB = haddr(l + 64, 0);   // = oaddrA + 288

    float y[6];
    #pragma unroll
    for (int s = 0; s < 6; ++s) y[s] = y0[row * 6 + s];

    if (w < 4 && l == 0) {
        #pragma unroll
        for (int s = 0; s < 6; ++s) out[(size_t)row * kT * 6 + s] = y[s];
    }

    const float* mrow = meal + (size_t)row * kT;
    const float* vrow = tvns + (size_t)row * kT;

    auto dyn = [&](float t, const float* yc, float m, float v, float* d) {
        if (w < 4 && l == 0) {
            float* xb = &xbuf[w * 16];
            xb[0]=t;     xb[1]=yc[0]; xb[2]=yc[1]; xb[3]=yc[2];
            xb[4]=yc[3]; xb[5]=yc[4]; xb[6]=yc[5]; xb[7]=yc[3]; xb[8]=v;
        }
        __syncthreads();

        // ---- input layer 9->128: this thread produces h0[r_p][j_p]
        {
            const f4* xr = (const f4*)(xbuf + r_p * 16);
            const f4 x0 = xr[0];
            const f4 x1 = xr[1];
            float s = bin + xbuf[r_p * 16 + 8] * win[8];
            s += x0.x * win[0] + x0.y * win[1] + x0.z * win[2] + x0.w * win[3];
            s += x1.x * win[4] + x1.y * win[5] + x1.z * win[6] + x1.w * win[7];
            hp0[waddr] = fast_tanh(s);
        }
        __syncthreads();

        // ---- 3 hidden layers 128->128
        #pragma unroll
        for (int ll = 0; ll < 3; ++ll) {
            const float* rb = (ll & 1) ? hp1 : hp0;
            float*       wb = (ll & 1) ? hp0 : hp1;

            // 8x ds_read_b128: each f4 = h[k][r=0..3]; acc_pj is f4 over rows
            // (components are distinct outputs -> no horizontal add needed).
            const f4* hb = (const f4*)(rb + 36 * kc);
            f4 acc0, acc1, acc2, acc3;
            {
                const f4 h = hb[0];
                const f4 wv = wgt[ll][0];
                acc0 = h * wv.x;
                acc1 = h * wv.y;
                acc2 = h * wv.z;
                acc3 = h * wv.w;
            }
            #pragma unroll
            for (int kk = 1; kk < 8; ++kk) {
                const f4 h = hb[kk];
                const f4 wv = wgt[ll][kk];
                acc0 += h * wv.x;
                acc1 += h * wv.y;
                acc2 += h * wv.z;
                acc3 += h * wv.w;
            }

            // Butterfly reduce-scatter over the 16 kc lanes; acc_pj[r] holds
            // out(j = jb + (pj^kch), row r) -> kc-bit2/3 stages are uniform.
            // stage kc-bit3: pairs (pj, pj^2), partner lane kc^8 (dpp row_ror:8)
            float B0[4], B1[4];
            #pragma unroll
            for (int r = 0; r < 4; ++r) {
                B0[r] = acc0[r] + dpp_ror8(acc2[r]);
                B1[r] = acc1[r] + dpp_ror8(acc3[r]);
            }
            // stage kc-bit2: pairs (B0, B1), partner lane kc^4 via ds_swizzle xor4
            float C[4];
            #pragma unroll
            for (int r = 0; r < 4; ++r)
                C[r] = B0[r] + swz<0x101F>(B1[r]);
            // stage kc-bit0 (r-bit0): keep/give select (rows, unavoidable)
            float D[2];
            #pragma unroll
            for (int i = 0; i < 2; ++i) {
                const float keep = pb0 ? C[2*i+1] : C[2*i];
                const float give = pb0 ? C[2*i]   : C[2*i+1];
                D[i] = keep + dpp_xor1(give);
            }
            // stage kc-bit1 (r-bit1)
            const float keep = pb1 ? D[1] : D[0];
            const float give = pb1 ? D[0] : D[1];
            const float S = keep + dpp_xor2(give);

            wb[waddr] = fast_tanh(S + bh[ll]);
            __syncthreads();
        }

        // ---- output layer 128->6 for this wave's row; h3 lives in hp1.
        // Reduce-scatter s to lane s8 (uniform, XOR'd weights), all-reduce the
        // eight 8-lane groups, then readlane-broadcast p[0..5] as wave scalars.
        const float hA = hp1[oaddrA + rw];
        const float hB = hp1[oaddrB + rw];
        float P[8];
        #pragma unroll
        for (int p = 0; p < 8; ++p) P[p] = hA * wo0p[p] + hB * wo1p[p];
        float Q[4];
        #pragma unroll
        for (int i = 0; i < 4; ++i) Q[i] = P[2*i] + dpp_xor1(P[2*i+1]);
        const float R0 = Q[0] + dpp_xor2(Q[1]);
        const float R1 = Q[2] + dpp_xor2(Q[3]);
        float S = R0 + swz<0x101F>(R1);   // xor4
        S += dpp_ror8(S);                 // xor8
        S += swz<0x401F>(S);              // xor16
        S += __shfl_xor(S, 32);           // xor32

        const float p0 = read_lane(S, 0);
        const float p1 = read_lane(S, 1);
        const float p2 = read_lane(S, 2);
        const float p3 = read_lane(S, 3);
        const float p4 = read_lane(S, 4);
        const float p5 = read_lane(S, 5);

        const float G = yc[0], I = yc[1], N = yc[2], L = yc[3], GE = yc[4], F = yc[5];
        d[0] = -0.01f*I*G + 0.05f*GE                                    + p0 + bo[0];
        d[1] = (G/(100.0f+G))*(1.0f + 2.0f*L/(5.0f+L)) - 0.1f*I         + p1 + bo[1];
        d[2] = -0.05f*N                                                 + p2 + bo[2];
        d[3] = 0.05f*GE - 0.2f*L                                        + p3 + bo[3];
        d[4] = m - 0.05f*GE                                             + p4 + bo[4];
        d[5] = -0.01f*I*F                                               + p5 + bo[5];
    };

    for (int i = 0; i < kT - 1; ++i) {
        const float t0 = t_span[i], t1 = t_span[i + 1];
        const float dt = t1 - t0;
        const float m0 = mrow[i], m1 = mrow[i + 1];
        const float v0 = vrow[i], v1 = vrow[i + 1];
        const float tm = t0 + 0.5f * dt;
        const float mm = 0.5f * (m0 + m1), vm = 0.5f * (v0 + v1);

        float d[6], ksum[6], yc[6];

        dyn(t0, y, m0, v0, d);
        #pragma unroll
        for (int s = 0; s < 6; ++s) { ksum[s] = d[s]; yc[s] = y[s] + 0.5f * dt * d[s]; }
        dyn(tm, yc, mm, vm, d);
        #pragma unroll
        for (int s = 0; s < 6; ++s) { ksum[s] += 2.0f * d[s]; yc[s] = y[s] + 0.5f * dt * d[s]; }
        dyn(tm, yc, mm, vm, d);
        #pragma unroll
        for (int s = 0; s < 6; ++s) { ksum[s] += 2.0f * d[s]; yc[s] = y[s] + dt * d[s]; }
        dyn(t1, yc, m1, v1, d);
        #pragma unroll
        for (int s = 0; s < 6; ++s) {
            ksum[s] += d[s];
            y[s] += (dt * (1.0f / 6.0f)) * ksum[s];
        }

        if (w < 4 && l == 0) {
            #pragma unroll
            for (int s = 0; s < 6; ++s)
                out[((size_t)row * kT + (i + 1)) * 6 + s] = y[s];
        }
    }
}

} // namespace

extern "C" void kernel_launch(void* const* d_in, const int* in_sizes, int n_in,
                              void* d_out, int out_size, void* d_ws, size_t ws_size,
                              hipStream_t stream) {
    const float* y0     = (const float*)d_in[0];
    const float* t_span = (const float*)d_in[1];
    const float* meal   = (const float*)d_in[2];
    const float* tvns   = (const float*)d_in[3];
    const float* W_in   = (const float*)d_in[4];
    const float* b_in   = (const float*)d_in[5];
    const float* W_h    = (const float*)d_in[6];
    const float* b_h    = (const float*)d_in[7];
    const float* W_out  = (const float*)d_in[8];
    const float* b_out  = (const float*)d_in[9];
    float* out          = (float*)d_out;

    hipLaunchKernelGGL(hybrid_ode_kernel, dim3(256), dim3(512), 0, stream,
                       y0, t_span, meal, tvns,
                       W_in, b_in, W_h, b_h, W_out, b_out, out);
}

// Round 6
// 2492.230 us; speedup vs baseline: 13.3363x; 13.3363x over previous
//
#include <hip/hip_runtime.h>

namespace {

constexpr int kT = 256;

typedef float f2 __attribute__((ext_vector_type(2)));
typedef float f4 __attribute__((ext_vector_type(4)));

__device__ __forceinline__ float fast_tanh(float x) {
    float e = __expf(2.0f * x);
    return 1.0f - 2.0f * __builtin_amdgcn_rcpf(e + 1.0f);
}

__device__ __forceinline__ float dpp_xor1(float x) {
    return __builtin_bit_cast(float, __builtin_amdgcn_update_dpp(
        0, __builtin_bit_cast(int, x), 0xB1, 0xF, 0xF, true)); // quad [1,0,3,2]
}
__device__ __forceinline__ float dpp_xor2(float x) {
    return __builtin_bit_cast(float, __builtin_amdgcn_update_dpp(
        0, __builtin_bit_cast(int, x), 0x4E, 0xF, 0xF, true)); // quad [2,3,0,1]
}
__device__ __forceinline__ float dpp_ror8(float x) {           // lane ^ 8 within row16
    return __builtin_bit_cast(float, __builtin_amdgcn_update_dpp(
        0, __builtin_bit_cast(int, x), 0x128, 0xF, 0xF, true)); // row_ror:8
}
template <int PAT>
__device__ __forceinline__ float swz(float x) {
    return __builtin_bit_cast(float,
        __builtin_amdgcn_ds_swizzle(__builtin_bit_cast(int, x), PAT));
}
__device__ __forceinline__ float read_lane(float x, int lane) {
    return __builtin_bit_cast(float,
        __builtin_amdgcn_readlane(__builtin_bit_cast(int, x), lane));
}

// h storage: element (k2,r,b) at float offset 8*k2 + 4*(k2>>2) + 2*r + b,
// where k2 = k>>1, b = k&1. f2 pair (k even, k odd) is contiguous; the
// pad 4*(k2>>2) spreads kc-chunks across banks (<=2-way everywhere).
// NOTE: the f2-pair core (this file) is the verified non-spilling structure
// (116 VGPR). The r-major f4-quad core spills to scratch at ANY launch
// bounds (r1/r2/r5: pinned 128 VGPR + 59 GB FETCH/dispatch). Do not re-land.
__device__ __forceinline__ int haddr(int j, int r) {
    return 8 * (j >> 1) + 4 * (j >> 3) + 2 * r + (j & 1);
}

__global__ __launch_bounds__(512, 1) void hybrid_ode_kernel(
    const float* __restrict__ y0,
    const float* __restrict__ t_span,
    const float* __restrict__ meal,
    const float* __restrict__ tvns,
    const float* __restrict__ W_in, const float* __restrict__ b_in,
    const float* __restrict__ W_h,  const float* __restrict__ b_h,
    const float* __restrict__ W_out,const float* __restrict__ b_out,
    float* __restrict__ out)
{
    const int tid = threadIdx.x;
    const int w   = tid >> 6;          // wave 0..7
    const int l   = tid & 63;
    const int jgl = l >> 4;            // 0..3 j-group within wave
    const int kc  = l & 15;            // k-chunk (8 k's)
    const int kch = kc >> 2;           // high 2 bits of kc (j-XOR key)
    const int jg  = w * 4 + jgl;       // 0..31
    const int jb  = jg * 4;            // thread's 4 j's: jb..jb+3 (XOR-permuted)
    const int rw  = w & 3;             // batch row this wave carries
    const int row = blockIdx.x * 4 + rw;

    // produced output slot after reduce-scatter
    const int r_p = kc & 3;
    const int j_p = jb + kch;
    const int waddr = haddr(j_p, r_p);
    const bool pb0 = (kc & 1) != 0;
    const bool pb1 = (kc & 2) != 0;

    __shared__ __align__(16) float hp0[576];
    __shared__ __align__(16) float hp1[576];

    // ---- one-time weight staging into registers
    // wgt[ll][ka][jj] holds column j = jb + (jj ^ kch): the j-XOR makes
    // butterfly stages 2/3 uniform (no keep/give selects there).
    f2 wgt[3][4][4];   // [layer][kpair kappa][jj]: k = 8kc+2*ka (+1)
    #pragma unroll
    for (int ll = 0; ll < 3; ++ll)
        #pragma unroll
        for (int ka = 0; ka < 4; ++ka)
            #pragma unroll
            for (int jj = 0; jj < 4; ++jj) {
                const float* p = W_h + (size_t)(ll * 128 + 8 * kc + 2 * ka) * 128
                               + jb + (jj ^ kch);
                f2 v; v.x = p[0]; v.y = p[128];
                wgt[ll][ka][jj] = v;
            }

    // Input layer is register-direct: waves w and w+4 produce row rw's h0
    // at column j2 = l + 64*(w>>2); the x-vector [t, y0..y5, y3, v] is
    // wave-uniform in registers, so no xbuf and no pre-input barrier.
    // win staged for j2 (used only in the input layer). The two y3 terms
    // (k=4 and k=7) are folded into one weight at staging time.
    const int j2 = l + 64 * (w >> 2);
    const int waddr2 = haddr(j2, rw);   // <=2-way bank aliasing over the wave
    float win[8];
    win[0] = W_in[0 * 128 + j2];                         // t
    win[1] = W_in[1 * 128 + j2];                         // y0
    win[2] = W_in[2 * 128 + j2];                         // y1
    win[3] = W_in[3 * 128 + j2];                         // y2
    win[4] = W_in[4 * 128 + j2] + W_in[7 * 128 + j2];    // y3 (+ glp1=y3)
    win[5] = W_in[5 * 128 + j2];                         // y4
    win[6] = W_in[6 * 128 + j2];                         // y5
    win[7] = W_in[8 * 128 + j2];                         // v
    const float bin = b_in[j2];

    float bh[3];
    #pragma unroll
    for (int ll = 0; ll < 3; ++ll) bh[ll] = b_h[ll * 128 + j_p];

    // output layer: XOR-permuted weights for a 3-bit reduce-scatter (s lands at l&7)
    const int s8 = l & 7;
    float wo0p[8], wo1p[8], bo[6];
    #pragma unroll
    for (int p = 0; p < 8; ++p) {
        const int q = p ^ s8;
        wo0p[p] = (q < 6) ? W_out[l * 6 + q] : 0.0f;
        wo1p[p] = (q < 6) ? W_out[(l + 64) * 6 + q] : 0.0f;
    }
    #pragma unroll
    for (int s = 0; s < 6; ++s) bo[s] = b_out[s];
    const int oaddr = 8 * (l >> 1) + 4 * (l >> 3) + (l & 1);  // + 2*rw at use

    float y[6];
    #pragma unroll
    for (int s = 0; s < 6; ++s) y[s] = y0[row * 6 + s];

    if (w < 4 && l == 0) {
        #pragma unroll
        for (int s = 0; s < 6; ++s) out[(size_t)row * kT * 6 + s] = y[s];
    }

    const float* mrow = meal + (size_t)row * kT;
    const float* vrow = tvns + (size_t)row * kT;

    auto dyn = [&](float t, const float* yc, float m, float v, float* d) {
        // ---- input layer 9->128, register-direct (no barrier needed before:
        // the previous dyn's last hp0 readers are ordered by the post-L2-write
        // barrier; output-layer reads touch hp1 only).
        {
            float s = bin + t * win[0];
            s += yc[0] * win[1] + yc[1] * win[2] + yc[2] * win[3];
            s += yc[3] * win[4] + yc[4] * win[5] + yc[5] * win[6];
            s += v * win[7];
            hp0[waddr2] = fast_tanh(s);
        }
        __syncthreads();

        // ---- 3 hidden layers 128->128
        #pragma unroll
        for (int ll = 0; ll < 3; ++ll) {
            const float* rb = (ll & 1) ? hp1 : hp0;
            float*       wb = (ll & 1) ? hp0 : hp1;

            f2 acc[4][4];   // [jj][r], packed over k-parity
            #pragma unroll
            for (int ka = 0; ka < 4; ++ka) {
                const int base = 36 * kc + 8 * ka;
                f4 q0 = *(const f4*)(rb + base);
                f4 q1 = *(const f4*)(rb + base + 4);
                f2 h0 = __builtin_shufflevector(q0, q0, 0, 1);
                f2 h1 = __builtin_shufflevector(q0, q0, 2, 3);
                f2 h2 = __builtin_shufflevector(q1, q1, 0, 1);
                f2 h3 = __builtin_shufflevector(q1, q1, 2, 3);
                #pragma unroll
                for (int jj = 0; jj < 4; ++jj) {
                    const f2 wv = wgt[ll][ka][jj];
                    if (ka == 0) {
                        acc[jj][0] = h0 * wv;
                        acc[jj][1] = h1 * wv;
                        acc[jj][2] = h2 * wv;
                        acc[jj][3] = h3 * wv;
                    } else {
                        acc[jj][0] = h0 * wv + acc[jj][0];
                        acc[jj][1] = h1 * wv + acc[jj][1];
                        acc[jj][2] = h2 * wv + acc[jj][2];
                        acc[jj][3] = h3 * wv + acc[jj][3];
                    }
                }
            }

            // horizontal add over k-parity; A indexed by out = (jj<<2)|r,
            // where the value is for column j = jb + (jj ^ kch), row r.
            float A[16];
            #pragma unroll
            for (int o = 0; o < 16; ++o)
                A[o] = acc[o >> 2][o & 3].x + acc[o >> 2][o & 3].y;

            // 4-stage reduce-scatter over the 16 kc lanes (same jg group).
            // Stages 0/1 key r-bits to kc-bits 0/1 (per-lane selects needed);
            // stages 2/3 are uniform thanks to the jj^kch weight permutation.
            float B[8];
            #pragma unroll
            for (int i = 0; i < 8; ++i) {
                float keep = pb0 ? A[2*i+1] : A[2*i];
                float give = pb0 ? A[2*i]   : A[2*i+1];
                B[i] = keep + dpp_xor1(give);
            }
            float C[4];
            #pragma unroll
            for (int i = 0; i < 4; ++i) {
                float keep = pb1 ? B[2*i+1] : B[2*i];
                float give = pb1 ? B[2*i]   : B[2*i+1];
                C[i] = keep + dpp_xor2(give);
            }
            float D[2];
            #pragma unroll
            for (int i = 0; i < 2; ++i)
                D[i] = C[2*i] + swz<0x101F>(C[2*i+1]);   // xor4, uniform
            float S = D[0] + dpp_ror8(D[1]);              // xor8, uniform

            wb[waddr] = fast_tanh(S + bh[ll]);
            __syncthreads();
        }

        // ---- output layer 128->6 for this wave's row; h3 lives in hp1.
        // Reduce-scatter s to lane s8 (uniform, XOR'd weights), all-reduce
        // the 8-lane groups, then readlane-broadcast p[0..5] as wave scalars.
        const float hA = hp1[oaddr + 2 * rw];
        const float hB = hp1[oaddr + 2 * rw + 288];
        float P[8];
        #pragma unroll
        for (int p = 0; p < 8; ++p) P[p] = hA * wo0p[p] + hB * wo1p[p];
        float Q[4];
        #pragma unroll
        for (int i = 0; i < 4; ++i) Q[i] = P[2*i] + dpp_xor1(P[2*i+1]);
        const float R0 = Q[0] + dpp_xor2(Q[1]);
        const float R1 = Q[2] + dpp_xor2(Q[3]);
        float S = R0 + swz<0x101F>(R1);   // xor4
        S += dpp_ror8(S);                 // xor8
        S += swz<0x401F>(S);              // xor16
        S += __shfl_xor(S, 32);           // xor32

        const float p0 = read_lane(S, 0);
        const float p1 = read_lane(S, 1);
        const float p2 = read_lane(S, 2);
        const float p3 = read_lane(S, 3);
        const float p4 = read_lane(S, 4);
        const float p5 = read_lane(S, 5);

        const float G = yc[0], I = yc[1], N = yc[2], L = yc[3], GE = yc[4], F = yc[5];
        d[0] = -0.01f*I*G + 0.05f*GE                                    + p0 + bo[0];
        d[1] = (G/(100.0f+G))*(1.0f + 2.0f*L/(5.0f+L)) - 0.1f*I         + p1 + bo[1];
        d[2] = -0.05f*N                                                 + p2 + bo[2];
        d[3] = 0.05f*GE - 0.2f*L                                        + p3 + bo[3];
        d[4] = m - 0.05f*GE                                             + p4 + bo[4];
        d[5] = -0.01f*I*F                                               + p5 + bo[5];
    };

    for (int i = 0; i < kT - 1; ++i) {
        const float t0 = t_span[i], t1 = t_span[i + 1];
        const float dt = t1 - t0;
        const float m0 = mrow[i], m1 = mrow[i + 1];
        const float v0 = vrow[i], v1 = vrow[i + 1];
        const float tm = t0 + 0.5f * dt;
        const float mm = 0.5f * (m0 + m1), vm = 0.5f * (v0 + v1);

        float d[6], ksum[6], yc[6];

        dyn(t0, y, m0, v0, d);
        #pragma unroll
        for (int s = 0; s < 6; ++s) { ksum[s] = d[s]; yc[s] = y[s] + 0.5f * dt * d[s]; }
        dyn(tm, yc, mm, vm, d);
        #pragma unroll
        for (int s = 0; s < 6; ++s) { ksum[s] += 2.0f * d[s]; yc[s] = y[s] + 0.5f * dt * d[s]; }
        dyn(tm, yc, mm, vm, d);
        #pragma unroll
        for (int s = 0; s < 6; ++s) { ksum[s] += 2.0f * d[s]; yc[s] = y[s] + dt * d[s]; }
        dyn(t1, yc, m1, v1, d);
        #pragma unroll
        for (int s = 0; s < 6; ++s) {
            ksum[s] += d[s];
            y[s] += (dt * (1.0f / 6.0f)) * ksum[s];
        }

        if (w < 4 && l == 0) {
            #pragma unroll
            for (int s = 0; s < 6; ++s)
                out[((size_t)row * kT + (i + 1)) * 6 + s] = y[s];
        }
    }
}

} // namespace

extern "C" void kernel_launch(void* const* d_in, const int* in_sizes, int n_in,
                              void* d_out, int out_size, void* d_ws, size_t ws_size,
                              hipStream_t stream) {
    const float* y0     = (const float*)d_in[0];
    const float* t_span = (const float*)d_in[1];
    const float* meal   = (const float*)d_in[2];
    const float* tvns   = (const float*)d_in[3];
    const float* W_in   = (const float*)d_in[4];
    const float* b_in   = (const float*)d_in[5];
    const float* W_h    = (const float*)d_in[6];
    const float* b_h    = (const float*)d_in[7];
    const float* W_out  = (const float*)d_in[8];
    const float* b_out  = (const float*)d_in[9];
    float* out          = (float*)d_out;

    hipLaunchKernelGGL(hybrid_ode_kernel, dim3(256), dim3(512), 0, stream,
                       y0, t_span, meal, tvns,
                       W_in, b_in, W_h, b_h, W_out, b_out, out);
}